// Round 18
// baseline (267.101 us; speedup 1.0000x reference)
//
#include <hip/hip_runtime.h>
#include <hip/hip_bf16.h>

typedef __attribute__((ext_vector_type(4))) float float4v;
typedef __attribute__((ext_vector_type(8))) __bf16 bf16x8;
typedef __attribute__((ext_vector_type(8))) unsigned short ushort8v;

constexpr int NTOK = 50176;
constexpr int DIM  = 384;
constexpr int HID  = 1536;
constexpr int BM   = 64;          // tokens/block
constexpr int NTH  = 512;
constexpr int NBLK = NTOK / BM;   // 784
constexpr int CHW  = 32;          // hidden chunk width
constexpr int NCH  = HID / CHW;   // 48

// workspace (byte offsets) — image formats IDENTICAL to R12/R17 (proven)
// W1-type [32 f][384 d]: 768B rows, pre-swizzled ^(f&7)<<4 — staged into LDS (x4 reuse)
// W2-type [384 d][32 k]: plain linear — B-frags read directly from global/L2 (x2 reuse)
constexpr int IMG_WD  = 0;                      // W1-type [32][384]
constexpr int IMG_WUP = 24576;                  // linear  [384][32]
constexpr int IMG_W1  = 49152;                  // 48 x W1-type
constexpr int IMG_W2  = 49152 + 48 * 12288 * 2; // 48 x linear
constexpr size_t WS_NEED = 2408448;
constexpr int NELEMS = 1204224;

// LDS (80 KiB/block => exactly 2 blocks/CU)
constexpr int L_X  = 0;        // 48K  X [64][384] bf16, 768B rows, swz (r&7)<<4 (persistent)
constexpr int L_W  = 49152;    // 24K  W1-chunk buffer (WD / W1c), swizzled rows
constexpr int L_HS = 73728;    // 8K   Hs double buffer: 2 x [64 tok][32 f] group-tiled
constexpr int LDSZ = 81920;

__device__ __forceinline__ unsigned short f2bf(float f) {
  __hip_bfloat16 h = __float2bfloat16(f);
  return *reinterpret_cast<unsigned short*>(&h);
}

__device__ __forceinline__ float gelu_f(float v) {
  float u = 0.7978845608f * (v + 0.044715f * v * v * v);
  float e = __expf(2.0f * u);
  float t = 1.0f - 2.0f / (e + 1.0f);
  return 0.5f * v * (1.0f + t);
}

// group-tiled byte address for [rows][32 cols] bf16: row r, 16B k-slot s
__device__ __forceinline__ int gt_addr(int r, int s) {
  return ((r >> 3) << 9) + (s << 7) + ((r & 7) << 4);
}

// ---- T14 staging (W1 only): load after barrier A, write after barrier B ----
__device__ __forceinline__ void st_load(const char* src, int tid, ushort8v st[3]) {
  #pragma unroll
  for (int j = 0; j < 3; ++j)
    st[j] = *(const ushort8v*)(src + tid * 16 + j * 8192);
}
__device__ __forceinline__ void st_wr(char* dst, int tid, const ushort8v st[3]) {
  #pragma unroll
  for (int j = 0; j < 3; ++j)
    *(ushort8v*)(dst + tid * 16 + j * 8192) = st[j];
}

// ---------------- pack kernel (identical to R12) ----------------
__global__ __launch_bounds__(256) void pack_k(
    const float* __restrict__ W1, const float* __restrict__ W2,
    const float* __restrict__ wd, const float* __restrict__ wu,
    unsigned short* __restrict__ img)
{
  int i = blockIdx.x * 256 + threadIdx.x;
  if (i >= NELEMS) return;
  if (i < 12288) {                               // WD (W1-type): [32 f][384 d] swz
    int f = i / 384; int inb = (i % 384) * 2;
    int d = (inb ^ ((f & 7) << 4)) >> 1;
    float v = (f < 24) ? wd[(f >> 3) * (DIM * 8) + d * 8 + (f & 7)] : 0.f;
    img[i] = f2bf(v);
  } else if (i < 24576) {                        // WUP linear [384 d][32 c]
    int j = i - 12288;
    int d = j / 32, c = j % 32;
    float v = (c < 24) ? wu[c * DIM + d] : 0.f;
    img[i] = f2bf(v);
  } else if (i < 24576 + 48 * 12288) {           // W1 chunks (W1-type swz)
    int j = i - 24576; int h = j / 12288; int jc = j % 12288;
    int f = jc / 384; int inb = (jc % 384) * 2;
    int d = (inb ^ ((f & 7) << 4)) >> 1;
    img[i] = f2bf(W1[d * HID + h * CHW + f]);
  } else {                                       // W2 chunks linear [384 d][32 k]
    int j = i - 24576 - 48 * 12288; int h = j / 12288; int jc = j % 12288;
    int d = jc / 32, k = jc % 32;
    img[i] = f2bf(W2[(h * CHW + k) * DIM + d]);
  }
}

// ---------------- fused MLP + MoE-LoRA ----------------
__global__ __launch_bounds__(NTH, 4) void fused_k(
    const float* __restrict__ x,
    const float* __restrict__ tp,
    const int*   __restrict__ ti,
    const float* __restrict__ b1,
    const float* __restrict__ b2,
    const unsigned short* __restrict__ img,
    float* __restrict__ out)
{
  extern __shared__ char lds[];
  const int tid = threadIdx.x, wid = tid >> 6, lane = tid & 63;
  const int lrow = lane & 15, g4 = lane >> 4;
  const int blockRow = blockIdx.x * BM;
  const char* imgc = (const char*)img;

  const int band = wid >> 1, chh = wid & 1;      // G1 grid: 4 bands x 2 col-halves
  const int wr = wid >> 2, wc = wid & 3;         // G2 grid: 2M x 4N

  ushort8v stg[3];                               // 12 regs; W1 pipeline only
  float4v accg[2][6] = {};                       // output accumulators (AGPR)

  // ---- prologue: issue WD; X f32->bf16 -> L_X ----
  st_load(imgc + IMG_WD, tid, stg);
  {
    const float* xb = x + (size_t)blockRow * DIM;
    #pragma unroll
    for (int it = 0; it < 6; ++it) {
      int idx = it * NTH + tid;
      int row = idx / 48, c8 = idx % 48;
      float4v v0 = *(const float4v*)(xb + row * DIM + c8 * 8);
      float4v v1 = *(const float4v*)(xb + row * DIM + c8 * 8 + 4);
      ushort8v u;
      u[0]=f2bf(v0[0]); u[1]=f2bf(v0[1]); u[2]=f2bf(v0[2]); u[3]=f2bf(v0[3]);
      u[4]=f2bf(v1[0]); u[5]=f2bf(v1[1]); u[6]=f2bf(v1[2]); u[7]=f2bf(v1[3]);
      int byte = (row * 768 + c8 * 16) ^ ((row & 7) << 4);
      *(ushort8v*)(lds + L_X + byte) = u;
    }
  }
  st_wr(lds + L_W, tid, stg);                    // WD -> L_W (reg-dep waits; hidden by X stage)
  st_load(imgc + IMG_W1, tid, stg);              // W1[0]; lands under G1-moe
  __syncthreads();                               // X + WD visible

  // ---- MoE chunk: G1 (with hoisted WUP B-loads) then G2 ----
  {
    bf16x8 bfr[6];
    #pragma unroll
    for (int nt = 0; nt < 6; ++nt) {
      int rd = wc * 96 + nt * 16 + lrow;
      bfr[nt] = *(const bf16x8*)(imgc + IMG_WUP + rd * 64 + g4 * 16);
    }
    float4v hv = {};
    {
      int raX = band * 16 + lrow, sA = (raX & 7) << 4, baX = raX * 768 + g4 * 16;
      int rbW = chh * 16 + lrow, sB = (rbW & 7) << 4, baW = rbW * 768 + g4 * 16;
      #pragma unroll
      for (int ks = 0; ks < 12; ++ks) {
        bf16x8 a = *(const bf16x8*)(lds + L_X + ((baX + ks * 64) ^ sA));
        bf16x8 b = *(const bf16x8*)(lds + L_W + ((baW + ks * 64) ^ sB));
        hv = __builtin_amdgcn_mfma_f32_16x16x32_bf16(a, b, hv, 0, 0, 0);
      }
    }
    {
      int colc = chh * 16 + lrow; int e = colc >> 3;
      #pragma unroll
      for (int r = 0; r < 4; ++r) {
        int row = band * 16 + g4 * 4 + r;
        int token = blockRow + row;
        float p = 0.f;
        if (e < 3) {
          int i0 = ti[token * 2], i1 = ti[token * 2 + 1];
          if (i0 == e) p += tp[token * 2];
          if (i1 == e) p += tp[token * 2 + 1];
        }
        float gv = p * gelu_f(hv[r]);
        int byte = gt_addr(row, colc >> 3) + ((colc & 7) << 1);
        *(unsigned short*)(lds + L_HS + byte) = f2bf(gv);
      }
    }
    __syncthreads();                             // bB-moe: Hs[0] visible; WD readers done
    st_wr(lds + L_W, tid, stg);                  // W1[0] -> L_W

    bf16x8 A[2];
    #pragma unroll
    for (int mt = 0; mt < 2; ++mt) {
      int ra = wr * 32 + mt * 16 + lrow;
      A[mt] = *(const bf16x8*)(lds + L_HS + gt_addr(ra, g4));
    }
    #pragma unroll
    for (int nt = 0; nt < 6; ++nt) {
      accg[0][nt] = __builtin_amdgcn_mfma_f32_16x16x32_bf16(A[0], bfr[nt], accg[0][nt], 0, 0, 0);
      accg[1][nt] = __builtin_amdgcn_mfma_f32_16x16x32_bf16(A[1], bfr[nt], accg[1][nt], 0, 0, 0);
    }
  }

  // ---- main loop: 48 chunks, 2 barriers/chunk; G2 B-loads hoisted above G1 ----
  for (int h = 0; h < NCH; ++h) {
    const int hb = 4096 - ((h & 1) << 12);       // G1[h] writes Hs[1-(h&1)]
    __syncthreads();                             // bA: W1[h] visible; Hs[target] readers done
    if (h < NCH - 1)
      st_load(imgc + IMG_W1 + (h + 1) * 24576, tid, stg);  // lands under G1

    bf16x8 bfr[6];                               // this chunk's G2 B-frags: fly across G1
    {
      const char* w2b = imgc + IMG_W2 + h * 24576;
      #pragma unroll
      for (int nt = 0; nt < 6; ++nt) {
        int rd = wc * 96 + nt * 16 + lrow;
        bfr[nt] = *(const bf16x8*)(w2b + rd * 64 + g4 * 16);
      }
    }
    float bb = b1[h * CHW + chh * 16 + lrow];

    // G1: H = X @ W1c -> [64][32]
    float4v hv = {};
    {
      int raX = band * 16 + lrow, sA = (raX & 7) << 4, baX = raX * 768 + g4 * 16;
      int rbW = chh * 16 + lrow, sB = (rbW & 7) << 4, baW = rbW * 768 + g4 * 16;
      #pragma unroll
      for (int ks = 0; ks < 12; ++ks) {
        bf16x8 a = *(const bf16x8*)(lds + L_X + ((baX + ks * 64) ^ sA));
        bf16x8 b = *(const bf16x8*)(lds + L_W + ((baW + ks * 64) ^ sB));
        hv = __builtin_amdgcn_mfma_f32_16x16x32_bf16(a, b, hv, 0, 0, 0);
      }
    }
    // bias + gelu -> Hs[target]
    {
      int colc = chh * 16 + lrow;
      #pragma unroll
      for (int r = 0; r < 4; ++r) {
        int row = band * 16 + g4 * 4 + r;
        float gv = gelu_f(hv[r] + bb);
        int byte = gt_addr(row, colc >> 3) + ((colc & 7) << 1);
        *(unsigned short*)(lds + L_HS + hb + byte) = f2bf(gv);
      }
    }
    __syncthreads();                             // bB: Hs visible; G1 done with L_W; bfr landed
    if (h < NCH - 1)
      st_wr(lds + L_W, tid, stg);                // W1[h+1] -> L_W

    // G2: acc += Hs @ W2c (K=32); B already in registers
    {
      bf16x8 A[2];
      #pragma unroll
      for (int mt = 0; mt < 2; ++mt) {
        int ra = wr * 32 + mt * 16 + lrow;
        A[mt] = *(const bf16x8*)(lds + L_HS + hb + gt_addr(ra, g4));
      }
      #pragma unroll
      for (int nt = 0; nt < 6; ++nt) {
        accg[0][nt] = __builtin_amdgcn_mfma_f32_16x16x32_bf16(A[0], bfr[nt], accg[0][nt], 0, 0, 0);
        accg[1][nt] = __builtin_amdgcn_mfma_f32_16x16x32_bf16(A[1], bfr[nt], accg[1][nt], 0, 0, 0);
      }
    }
  }

  // ---- epilogue: + b2, store f32 ----
  #pragma unroll
  for (int nt = 0; nt < 6; ++nt) {
    int col = wc * 96 + nt * 16 + lrow;
    float bb = b2[col];
    #pragma unroll
    for (int mt = 0; mt < 2; ++mt) {
      #pragma unroll
      for (int r = 0; r < 4; ++r) {
        int row = wr * 32 + mt * 16 + g4 * 4 + r;
        out[(size_t)(blockRow + row) * DIM + col] = accg[mt][nt][r] + bb;
      }
    }
  }
}

extern "C" void kernel_launch(void* const* d_in, const int* in_sizes, int n_in,
                              void* d_out, int out_size, void* d_ws, size_t ws_size,
                              hipStream_t stream) {
  const float* x          = (const float*)d_in[0];
  const float* topk_probs = (const float*)d_in[2];
  const int*   topk_idx   = (const int*)  d_in[3];
  const float* w_down     = (const float*)d_in[4];
  const float* w_up       = (const float*)d_in[5];
  const float* W1         = (const float*)d_in[6];
  const float* b1         = (const float*)d_in[7];
  const float* W2         = (const float*)d_in[8];
  const float* b2         = (const float*)d_in[9];
  float* out = (float*)d_out;

  if (ws_size < WS_NEED) return;

  hipFuncSetAttribute(reinterpret_cast<const void*>(fused_k),
                      hipFuncAttributeMaxDynamicSharedMemorySize, LDSZ);

  unsigned short* img = (unsigned short*)d_ws;
  pack_k<<<(NELEMS + 255) / 256, 256, 0, stream>>>(W1, W2, w_down, w_up, img);
  fused_k<<<NBLK, NTH, LDSZ, stream>>>(x, topk_probs, topk_idx, b1, b2, img, out);
}

// Round 19
// 266.832 us; speedup vs baseline: 1.0010x; 1.0010x over previous
//
#include <hip/hip_runtime.h>
#include <hip/hip_bf16.h>

typedef __attribute__((ext_vector_type(4))) float float4v;
typedef __attribute__((ext_vector_type(8))) __bf16 bf16x8;
typedef __attribute__((ext_vector_type(8))) unsigned short ushort8v;

constexpr int NTOK = 50176;
constexpr int DIM  = 384;
constexpr int HID  = 1536;
constexpr int BM   = 64;          // tokens/block
constexpr int NTH  = 512;
constexpr int NBLK = NTOK / BM;   // 784
constexpr int CHW  = 32;          // hidden chunk width
constexpr int NCH  = HID / CHW;   // 48

// workspace (byte offsets) — image formats IDENTICAL to R12/R17 (proven)
// W1-type [32 f][384 d]: 768B rows, pre-swizzled ^(f&7)<<4 — staged into LDS (x4 reuse)
// W2-type [384 d][32 k]: plain linear — B-frags read directly from global/L2 (x2 reuse)
constexpr int IMG_WD  = 0;                      // W1-type [32][384]
constexpr int IMG_WUP = 24576;                  // linear  [384][32]
constexpr int IMG_W1  = 49152;                  // 48 x W1-type
constexpr int IMG_W2  = 49152 + 48 * 12288 * 2; // 48 x linear
constexpr size_t WS_NEED = 2408448;
constexpr int NELEMS = 1204224;

// LDS (80 KiB/block => exactly 2 blocks/CU)
constexpr int L_X  = 0;        // 48K  X [64][384] bf16, 768B rows, swz (r&7)<<4 (persistent)
constexpr int L_W  = 49152;    // 24K  W1-chunk buffer (WD / W1c), swizzled rows
constexpr int L_HS = 73728;    // 8K   Hs double buffer: 2 x [64 tok][32 f] group-tiled
constexpr int LDSZ = 81920;

__device__ __forceinline__ unsigned short f2bf(float f) {
  __hip_bfloat16 h = __float2bfloat16(f);
  return *reinterpret_cast<unsigned short*>(&h);
}

__device__ __forceinline__ float gelu_f(float v) {
  float u = 0.7978845608f * (v + 0.044715f * v * v * v);
  float e = __expf(2.0f * u);
  float t = 1.0f - 2.0f / (e + 1.0f);
  return 0.5f * v * (1.0f + t);
}

// group-tiled byte address for [rows][32 cols] bf16: row r, 16B k-slot s
__device__ __forceinline__ int gt_addr(int r, int s) {
  return ((r >> 3) << 9) + (s << 7) + ((r & 7) << 4);
}

// ---- T14 staging (W1 only): load after barrier A, write after barrier B ----
__device__ __forceinline__ void st_load(const char* src, int tid, ushort8v st[3]) {
  #pragma unroll
  for (int j = 0; j < 3; ++j)
    st[j] = *(const ushort8v*)(src + tid * 16 + j * 8192);
}
__device__ __forceinline__ void st_wr(char* dst, int tid, const ushort8v st[3]) {
  #pragma unroll
  for (int j = 0; j < 3; ++j)
    *(ushort8v*)(dst + tid * 16 + j * 8192) = st[j];
}

// ---------------- pack kernel (identical to R12) ----------------
__global__ __launch_bounds__(256) void pack_k(
    const float* __restrict__ W1, const float* __restrict__ W2,
    const float* __restrict__ wd, const float* __restrict__ wu,
    unsigned short* __restrict__ img)
{
  int i = blockIdx.x * 256 + threadIdx.x;
  if (i >= NELEMS) return;
  if (i < 12288) {                               // WD (W1-type): [32 f][384 d] swz
    int f = i / 384; int inb = (i % 384) * 2;
    int d = (inb ^ ((f & 7) << 4)) >> 1;
    float v = (f < 24) ? wd[(f >> 3) * (DIM * 8) + d * 8 + (f & 7)] : 0.f;
    img[i] = f2bf(v);
  } else if (i < 24576) {                        // WUP linear [384 d][32 c]
    int j = i - 12288;
    int d = j / 32, c = j % 32;
    float v = (c < 24) ? wu[c * DIM + d] : 0.f;
    img[i] = f2bf(v);
  } else if (i < 24576 + 48 * 12288) {           // W1 chunks (W1-type swz)
    int j = i - 24576; int h = j / 12288; int jc = j % 12288;
    int f = jc / 384; int inb = (jc % 384) * 2;
    int d = (inb ^ ((f & 7) << 4)) >> 1;
    img[i] = f2bf(W1[d * HID + h * CHW + f]);
  } else {                                       // W2 chunks linear [384 d][32 k]
    int j = i - 24576 - 48 * 12288; int h = j / 12288; int jc = j % 12288;
    int d = jc / 32, k = jc % 32;
    img[i] = f2bf(W2[(h * CHW + k) * DIM + d]);
  }
}

// ---------------- fused MLP + MoE-LoRA ----------------
__global__ __launch_bounds__(NTH, 4) void fused_k(
    const float* __restrict__ x,
    const float* __restrict__ tp,
    const int*   __restrict__ ti,
    const float* __restrict__ b1,
    const float* __restrict__ b2,
    const unsigned short* __restrict__ img,
    float* __restrict__ out)
{
  extern __shared__ char lds[];
  const int tid = threadIdx.x, wid = tid >> 6, lane = tid & 63;
  const int lrow = lane & 15, g4 = lane >> 4;
  const int blockRow = blockIdx.x * BM;
  const char* imgc = (const char*)img;

  const int band = wid >> 1, chh = wid & 1;      // G1 grid: 4 bands x 2 col-halves
  const int wr = wid >> 2, wc = wid & 3;         // G2 grid: 2M x 4N

  ushort8v stg[3];                               // 12 regs; W1 pipeline only
  float4v accg[2][6] = {};                       // output accumulators (AGPR)

  // ---- prologue: issue WD; X f32->bf16 -> L_X ----
  st_load(imgc + IMG_WD, tid, stg);
  {
    const float* xb = x + (size_t)blockRow * DIM;
    #pragma unroll
    for (int it = 0; it < 6; ++it) {
      int idx = it * NTH + tid;
      int row = idx / 48, c8 = idx % 48;
      float4v v0 = *(const float4v*)(xb + row * DIM + c8 * 8);
      float4v v1 = *(const float4v*)(xb + row * DIM + c8 * 8 + 4);
      ushort8v u;
      u[0]=f2bf(v0[0]); u[1]=f2bf(v0[1]); u[2]=f2bf(v0[2]); u[3]=f2bf(v0[3]);
      u[4]=f2bf(v1[0]); u[5]=f2bf(v1[1]); u[6]=f2bf(v1[2]); u[7]=f2bf(v1[3]);
      int byte = (row * 768 + c8 * 16) ^ ((row & 7) << 4);
      *(ushort8v*)(lds + L_X + byte) = u;
    }
  }
  st_wr(lds + L_W, tid, stg);                    // WD -> L_W (reg-dep waits; hidden by X stage)
  st_load(imgc + IMG_W1, tid, stg);              // W1[0]; lands under G1-moe
  __syncthreads();                               // X + WD visible

  // ---- MoE chunk: G1 (partial-hoisted WUP B-loads) then G2 ----
  {
    float4v hv = {};
    {
      int raX = band * 16 + lrow, sA = (raX & 7) << 4, baX = raX * 768 + g4 * 16;
      int rbW = chh * 16 + lrow, sB = (rbW & 7) << 4, baW = rbW * 768 + g4 * 16;
      #pragma unroll
      for (int ks = 0; ks < 12; ++ks) {
        bf16x8 a = *(const bf16x8*)(lds + L_X + ((baX + ks * 64) ^ sA));
        bf16x8 b = *(const bf16x8*)(lds + L_W + ((baW + ks * 64) ^ sB));
        hv = __builtin_amdgcn_mfma_f32_16x16x32_bf16(a, b, hv, 0, 0, 0);
      }
    }
    // partial hoist: WUP B-loads fly over the gelu/Hs-write block + barrier
    bf16x8 bfr[6];
    #pragma unroll
    for (int nt = 0; nt < 6; ++nt) {
      int rd = wc * 96 + nt * 16 + lrow;
      bfr[nt] = *(const bf16x8*)(imgc + IMG_WUP + rd * 64 + g4 * 16);
    }
    {
      int colc = chh * 16 + lrow; int e = colc >> 3;
      #pragma unroll
      for (int r = 0; r < 4; ++r) {
        int row = band * 16 + g4 * 4 + r;
        int token = blockRow + row;
        float p = 0.f;
        if (e < 3) {
          int i0 = ti[token * 2], i1 = ti[token * 2 + 1];
          if (i0 == e) p += tp[token * 2];
          if (i1 == e) p += tp[token * 2 + 1];
        }
        float gv = p * gelu_f(hv[r]);
        int byte = gt_addr(row, colc >> 3) + ((colc & 7) << 1);
        *(unsigned short*)(lds + L_HS + byte) = f2bf(gv);
      }
    }
    __syncthreads();                             // bB-moe: Hs[0] visible; WD readers done
    st_wr(lds + L_W, tid, stg);                  // W1[0] -> L_W

    bf16x8 A[2];
    #pragma unroll
    for (int mt = 0; mt < 2; ++mt) {
      int ra = wr * 32 + mt * 16 + lrow;
      A[mt] = *(const bf16x8*)(lds + L_HS + gt_addr(ra, g4));
    }
    #pragma unroll
    for (int nt = 0; nt < 6; ++nt) {
      accg[0][nt] = __builtin_amdgcn_mfma_f32_16x16x32_bf16(A[0], bfr[nt], accg[0][nt], 0, 0, 0);
      accg[1][nt] = __builtin_amdgcn_mfma_f32_16x16x32_bf16(A[1], bfr[nt], accg[1][nt], 0, 0, 0);
    }
  }

  // ---- main loop: 48 chunks, 2 barriers/chunk; G2 B-loads partial-hoisted ----
  for (int h = 0; h < NCH; ++h) {
    const int hb = 4096 - ((h & 1) << 12);       // G1[h] writes Hs[1-(h&1)]
    __syncthreads();                             // bA: W1[h] visible; Hs[target] readers done
    if (h < NCH - 1)
      st_load(imgc + IMG_W1 + (h + 1) * 24576, tid, stg);  // lands under G1

    float bb = b1[h * CHW + chh * 16 + lrow];

    // G1: H = X @ W1c -> [64][32]  (register peak kept at R17 level)
    float4v hv = {};
    {
      int raX = band * 16 + lrow, sA = (raX & 7) << 4, baX = raX * 768 + g4 * 16;
      int rbW = chh * 16 + lrow, sB = (rbW & 7) << 4, baW = rbW * 768 + g4 * 16;
      #pragma unroll
      for (int ks = 0; ks < 12; ++ks) {
        bf16x8 a = *(const bf16x8*)(lds + L_X + ((baX + ks * 64) ^ sA));
        bf16x8 b = *(const bf16x8*)(lds + L_W + ((baW + ks * 64) ^ sB));
        hv = __builtin_amdgcn_mfma_f32_16x16x32_bf16(a, b, hv, 0, 0, 0);
      }
    }
    // partial hoist: issue G2 B-loads NOW — they fly over gelu + Hs writes + bB
    bf16x8 bfr[6];
    {
      const char* w2b = imgc + IMG_W2 + h * 24576;
      #pragma unroll
      for (int nt = 0; nt < 6; ++nt) {
        int rd = wc * 96 + nt * 16 + lrow;
        bfr[nt] = *(const bf16x8*)(w2b + rd * 64 + g4 * 16);
      }
    }
    // bias + gelu -> Hs[target]
    {
      int colc = chh * 16 + lrow;
      #pragma unroll
      for (int r = 0; r < 4; ++r) {
        int row = band * 16 + g4 * 4 + r;
        float gv = gelu_f(hv[r] + bb);
        int byte = gt_addr(row, colc >> 3) + ((colc & 7) << 1);
        *(unsigned short*)(lds + L_HS + hb + byte) = f2bf(gv);
      }
    }
    __syncthreads();                             // bB: Hs visible; G1 done with L_W; bfr landed
    if (h < NCH - 1)
      st_wr(lds + L_W, tid, stg);                // W1[h+1] -> L_W

    // G2: acc += Hs @ W2c (K=32); B already in registers
    {
      bf16x8 A[2];
      #pragma unroll
      for (int mt = 0; mt < 2; ++mt) {
        int ra = wr * 32 + mt * 16 + lrow;
        A[mt] = *(const bf16x8*)(lds + L_HS + hb + gt_addr(ra, g4));
      }
      #pragma unroll
      for (int nt = 0; nt < 6; ++nt) {
        accg[0][nt] = __builtin_amdgcn_mfma_f32_16x16x32_bf16(A[0], bfr[nt], accg[0][nt], 0, 0, 0);
        accg[1][nt] = __builtin_amdgcn_mfma_f32_16x16x32_bf16(A[1], bfr[nt], accg[1][nt], 0, 0, 0);
      }
    }
  }

  // ---- epilogue: + b2, store f32 ----
  #pragma unroll
  for (int nt = 0; nt < 6; ++nt) {
    int col = wc * 96 + nt * 16 + lrow;
    float bb = b2[col];
    #pragma unroll
    for (int mt = 0; mt < 2; ++mt) {
      #pragma unroll
      for (int r = 0; r < 4; ++r) {
        int row = wr * 32 + mt * 16 + g4 * 4 + r;
        out[(size_t)(blockRow + row) * DIM + col] = accg[mt][nt][r] + bb;
      }
    }
  }
}

extern "C" void kernel_launch(void* const* d_in, const int* in_sizes, int n_in,
                              void* d_out, int out_size, void* d_ws, size_t ws_size,
                              hipStream_t stream) {
  const float* x          = (const float*)d_in[0];
  const float* topk_probs = (const float*)d_in[2];
  const int*   topk_idx   = (const int*)  d_in[3];
  const float* w_down     = (const float*)d_in[4];
  const float* w_up       = (const float*)d_in[5];
  const float* W1         = (const float*)d_in[6];
  const float* b1         = (const float*)d_in[7];
  const float* W2         = (const float*)d_in[8];
  const float* b2         = (const float*)d_in[9];
  float* out = (float*)d_out;

  if (ws_size < WS_NEED) return;

  hipFuncSetAttribute(reinterpret_cast<const void*>(fused_k),
                      hipFuncAttributeMaxDynamicSharedMemorySize, LDSZ);

  unsigned short* img = (unsigned short*)d_ws;
  pack_k<<<(NELEMS + 255) / 256, 256, 0, stream>>>(W1, W2, w_down, w_up, img);
  fused_k<<<NBLK, NTH, LDSZ, stream>>>(x, topk_probs, topk_idx, b1, b2, img, out);
}